// Round 3
// baseline (1010.250 us; speedup 1.0000x reference)
//
#include <hip/hip_runtime.h>
#include <stdint.h>

#define NNODES 50000
#define NEDGES 800000
#define CDIM   64
#define SHD    9
#define EBD    16

using f32x4  = __attribute__((ext_vector_type(4))) float;
using bf16x8 = __attribute__((ext_vector_type(8))) __bf16;

static __device__ __forceinline__ unsigned short bfr(float x) {
  union { __bf16 b; unsigned short u; } t;
  t.b = (__bf16)x;            // native cvt, RNE
  return t.u;
}
static __device__ __forceinline__ float bf2f(unsigned short b) {
  union { unsigned u; float f; } v; v.u = ((unsigned)b) << 16;
  return v.f;
}
static __device__ __forceinline__ f32x4 mfma16(bf16x8 a, bf16x8 b, f32x4 c) {
  return __builtin_amdgcn_mfma_f32_16x16x32_bf16(a, b, c, 0, 0, 0);
}
static __device__ __forceinline__ ushort4 cvt4(float4 v) {
  return make_ushort4(bfr(v.x), bfr(v.y), bfr(v.z), bfr(v.w));
}
static __device__ __forceinline__ bf16x8 pack8(float4 a, float4 b) {
  union { unsigned short u[8]; bf16x8 v; } t;
  t.u[0]=bfr(a.x); t.u[1]=bfr(a.y); t.u[2]=bfr(a.z); t.u[3]=bfr(a.w);
  t.u[4]=bfr(b.x); t.u[5]=bfr(b.y); t.u[6]=bfr(b.z); t.u[7]=bfr(b.w);
  return t.v;
}
static __device__ __forceinline__ bf16x8 ldA(const unsigned short* __restrict__ p, int idx) {
  union { uint4 q; bf16x8 v; } t;
  t.q = reinterpret_cast<const uint4*>(p)[idx];
  return t.v;
}
static __device__ __forceinline__ bf16x8 ldL(const unsigned short* p) {
  union { uint4 q; bf16x8 v; } t;
  t.q = *reinterpret_cast<const uint4*>(p);
  return t.v;
}

// Pack fp32 w[K][N] -> bf16 fragment order (identical for A- and B-operand use):
// dst[((nt*KS+ks)*64+lane)*8+j] = w[rowmap(ks*32+(lane>>4)*8+j)][nt*16+(lane&15)]
// mode 1 (w_tp): vt col space [v16|fe9|z3|fes16|z20] -> w rows {c, c-7, c-10}.
__global__ void pack_all_kernel(
    const float* __restrict__ wev1, const float* __restrict__ weu1,
    const float* __restrict__ wnl1, const float* __restrict__ weu2,
    const float* __restrict__ wnl2, const float* __restrict__ wev2,
    const float* __restrict__ wtp,
    unsigned short* __restrict__ pev1, unsigned short* __restrict__ peu1,
    unsigned short* __restrict__ pnl1, unsigned short* __restrict__ peu2,
    unsigned short* __restrict__ pnl2, unsigned short* __restrict__ pev2,
    unsigned short* __restrict__ ptp) {
  int b = blockIdx.x;
  const float* w; unsigned short* dst; int K, N, KS, NT, base, mode = 0;
  if (b < 24)      { w = wev1; dst = pev1; K = 192; N = 256; KS = 6; NT = 16; base = 0; }
  else if (b < 48) { w = weu1; dst = peu1; K = 192; N = 256; KS = 6; NT = 16; base = 24; }
  else if (b < 64) { w = wnl1; dst = pnl1; K = 128; N = 256; KS = 4; NT = 16; base = 48; }
  else if (b < 72) { w = weu2; dst = peu2; K = 256; N = 64;  KS = 8; NT = 4;  base = 64; }
  else if (b < 80) { w = wnl2; dst = pnl2; K = 256; N = 64;  KS = 8; NT = 4;  base = 72; }
  else if (b < 82) { w = wev2; dst = pev2; K = 256; N = 9;   KS = 8; NT = 1;  base = 80; }
  else             { w = wtp;  dst = ptp;  K = 34;  N = 64;  KS = 2; NT = 4;  base = 82; mode = 1; }
  int idx = (b - base) * 256 + threadIdx.x;
  int total = NT * KS * 64;
  if (idx >= total) return;
  int lane = idx & 63;
  int t = idx >> 6;
  int ks = t % KS;
  int nt = t / KS;
  int n  = nt * 16 + (lane & 15);
  int kb = ks * 32 + ((lane >> 4) << 3);
  unsigned short v[8];
#pragma unroll
  for (int j = 0; j < 8; ++j) {
    int k = kb + j;
    int rm;
    if (mode == 0) rm = (k < K) ? k : -1;
    else rm = (k < 9) ? k : (k >= 16 && k <= 24) ? k - 7 : (k >= 28 && k <= 43) ? k - 10 : -1;
    float val = (rm >= 0 && n < N) ? w[(size_t)rm * N + n] : 0.f;
    v[j] = bfr(val);
  }
  uint4 pk;
  pk.x = (unsigned)v[0] | ((unsigned)v[1] << 16);
  pk.y = (unsigned)v[2] | ((unsigned)v[3] << 16);
  pk.z = (unsigned)v[4] | ((unsigned)v[5] << 16);
  pk.w = (unsigned)v[6] | ((unsigned)v[7] << 16);
  reinterpret_cast<uint4*>(dst)[idx] = pk;
}

// Swapped-operand, wave-independent edge pipeline.
// 4 waves/block, 16 edges/wave, NO __syncthreads. C always: edge=lane&15,
// feature=(lane>>4)*4+r -> b64 ring write, b128 frag read.
__global__ __launch_bounds__(256, 4) void edge_kernel(
    const float* __restrict__ hn, const float* __restrict__ he,
    const float* __restrict__ fe, const float* __restrict__ fes,
    const float* __restrict__ nrm,
    const int* __restrict__ esrc, const int* __restrict__ edst,
    const unsigned short* __restrict__ pev1, const float* __restrict__ bev1,
    const unsigned short* __restrict__ pev2, const float* __restrict__ bev2,
    const unsigned short* __restrict__ ptp,  const float* __restrict__ btp,
    const unsigned short* __restrict__ peu1, const float* __restrict__ beu1,
    const unsigned short* __restrict__ peu2, const float* __restrict__ beu2,
    float* __restrict__ out_he, float* __restrict__ nf) {
  __shared__ unsigned short xa[4][16][136];  // [hs|hd] per-wave (stride 272B: 16-aligned, 2-way banks)
  __shared__ unsigned short vt[4][16][72];   // [v16|fe9|z3|fes16|z20] per-wave
  __shared__ unsigned short tb[4][16][72];   // ring (GEMM1->2, GEMM3->4) then t-buffer

  const int tid  = threadIdx.x;
  const int lane = tid & 63;
  const int wid  = tid >> 6;
  const int eb   = blockIdx.x * 64;
  const int e    = lane & 15;
  const int g    = lane >> 4;
  const int koff = g << 3;
  const int eg   = eb + wid * 16 + e;

  // ---- staging (wave-private rows: thread t handles edge t>>2 which belongs to wave t>>6) ----
  {
    const int et  = tid >> 2;        // 0..63
    const int el  = et & 15;
    const int q   = tid & 3;
    const int cg  = q << 4;
    const int ege = eb + et;
    const int src = esrc[ege];
    const int dst = edst[ege];
    const float4* hsP = reinterpret_cast<const float4*>(hn + (size_t)src * 64 + cg);
    const float4* hdP = reinterpret_cast<const float4*>(hn + (size_t)dst * 64 + cg);
#pragma unroll
    for (int i = 0; i < 4; ++i) {
      float4 b = hsP[i], d = hdP[i];
      *reinterpret_cast<ushort4*>(&xa[wid][el][cg + i * 4])      = cvt4(b);
      *reinterpret_cast<ushort4*>(&xa[wid][el][64 + cg + i * 4]) = cvt4(d);
    }
    // vt zero-init (cols q*16 .. q*16+15)
    uint4 z = {0, 0, 0, 0};
    *reinterpret_cast<uint4*>(&vt[wid][el][cg])     = z;
    *reinterpret_cast<uint4*>(&vt[wid][el][cg + 8]) = z;
    // fe -> cols 16..24
    vt[wid][el][16 + q]     = bfr(fe[(size_t)ege * SHD + q]);
    vt[wid][el][16 + q + 4] = bfr(fe[(size_t)ege * SHD + q + 4]);
    if (q == 0) vt[wid][el][24] = bfr(fe[(size_t)ege * SHD + 8]);
    // fes -> cols 28..43
    float4 fs = *reinterpret_cast<const float4*>(fes + (size_t)ege * EBD + q * 4);
    *reinterpret_cast<ushort4*>(&vt[wid][el][28 + q * 4]) = cvt4(fs);
  }
  // no barrier: all LDS rows used below were written by this same wave (in-order LDS).

  // ---- persistent B-fragments (x^T): he direct from global, hs/hd from xa ----
  bf16x8 bhe0, bhe1;
  {
    const float4* heP = reinterpret_cast<const float4*>(he + (size_t)eg * 64);
    bhe0 = pack8(heP[koff >> 2], heP[(koff >> 2) + 1]);          // features 0..31
    bhe1 = pack8(heP[(32 + koff) >> 2], heP[((32 + koff) >> 2) + 1]); // 32..63
  }
  bf16x8 bx[4];
#pragma unroll
  for (int s = 0; s < 4; ++s)
    bx[s] = ldL(&xa[wid][e][s * 32 + koff]);   // features 64..191 (hs|hd)

  // ---- GEMM1 (a1^T = w_ev1^T @ x^T) fused with GEMM2 (v^T = w_ev2^T @ a1^T) ----
  f32x4 accv = (f32x4){0.f, 0.f, 0.f, 0.f};
#pragma unroll
  for (int mt = 0; mt < 16; ++mt) {
    f32x4 c = (f32x4){0.f, 0.f, 0.f, 0.f};
    c = mfma16(ldA(pev1, (mt * 6 + 0) * 64 + lane), bhe0, c);
    c = mfma16(ldA(pev1, (mt * 6 + 1) * 64 + lane), bhe1, c);
#pragma unroll
    for (int s = 0; s < 4; ++s)
      c = mfma16(ldA(pev1, (mt * 6 + 2 + s) * 64 + lane), bx[s], c);
    float4 bias = *reinterpret_cast<const float4*>(&bev1[mt * 16 + g * 4]);
    float4 cv = {c[0] + bias.x, c[1] + bias.y, c[2] + bias.z, c[3] + bias.w};
    cv.x = cv.x > 0.f ? cv.x : 0.f;  cv.y = cv.y > 0.f ? cv.y : 0.f;
    cv.z = cv.z > 0.f ? cv.z : 0.f;  cv.w = cv.w > 0.f ? cv.w : 0.f;
    const int slot = (mt >> 1) & 1;
    *reinterpret_cast<ushort4*>(&tb[wid][e][slot * 32 + (mt & 1) * 16 + g * 4]) = cvt4(cv);
    // consume previous pair (1-iteration delay hides LDS round-trip)
    if ((mt & 1) == 0 && mt >= 2) {
      const int kt = (mt - 2) >> 1;
      bf16x8 b2 = ldL(&tb[wid][e][(kt & 1) * 32 + koff]);
      accv = mfma16(ldA(pev2, kt * 64 + lane), b2, accv);
    }
    if ((mt & 3) == 3) __builtin_amdgcn_s_barrier();   // timing alignment only (L1 reuse)
  }
  {  // last kt = 7 (slot 1)
    bf16x8 b2 = ldL(&tb[wid][e][32 + koff]);
    accv = mfma16(ldA(pev2, 7 * 64 + lane), b2, accv);
  }

  // ---- v -> vt cols 0..15 (vcol >= 9 forced to 0) ----
  {
    float4 bv = {0.f, 0.f, 0.f, 0.f};
    if (g < 2)       bv = *reinterpret_cast<const float4*>(&bev2[g * 4]);
    else if (g == 2) bv.x = bev2[8];
    float vals[4] = {accv[0] + bv.x, accv[1] + bv.y, accv[2] + bv.z, accv[3] + bv.w};
    ushort4 uv;
    uv.x = (g * 4 + 0 < 9) ? bfr(vals[0]) : (unsigned short)0;
    uv.y = (g * 4 + 1 < 9) ? bfr(vals[1]) : (unsigned short)0;
    uv.z = (g * 4 + 2 < 9) ? bfr(vals[2]) : (unsigned short)0;
    uv.w = (g * 4 + 3 < 9) ? bfr(vals[3]) : (unsigned short)0;
    *reinterpret_cast<ushort4*>(&vt[wid][e][g * 4]) = uv;
  }

  // ---- GEMM_t (t^T = w_tp^T @ [v|fe|fes]^T), K padded to 64 ----
  {
    bf16x8 btv0 = ldL(&vt[wid][e][koff]);
    bf16x8 btv1 = ldL(&vt[wid][e][32 + koff]);
#pragma unroll
    for (int mt = 0; mt < 4; ++mt) {
      f32x4 c = (f32x4){0.f, 0.f, 0.f, 0.f};
      c = mfma16(ldA(ptp, (mt * 2 + 0) * 64 + lane), btv0, c);
      c = mfma16(ldA(ptp, (mt * 2 + 1) * 64 + lane), btv1, c);
      float4 bias = *reinterpret_cast<const float4*>(&btp[mt * 16 + g * 4]);
      float4 cv = {c[0] + bias.x, c[1] + bias.y, c[2] + bias.z, c[3] + bias.w};
      *reinterpret_cast<ushort4*>(&tb[wid][e][mt * 16 + g * 4]) = cvt4(cv);
    }
  }

  // ---- GEMM3 (a2^T = w_eu1^T @ [t|hs|hd]^T) fused with GEMM4 ----
  bf16x8 bt0 = ldL(&tb[wid][e][koff]);        // t features 0..31
  bf16x8 bt1 = ldL(&tb[wid][e][32 + koff]);   // t features 32..63
  f32x4 acc4[4];
#pragma unroll
  for (int n = 0; n < 4; ++n) acc4[n] = (f32x4){0.f, 0.f, 0.f, 0.f};
#pragma unroll
  for (int mt = 0; mt < 16; ++mt) {
    f32x4 c = (f32x4){0.f, 0.f, 0.f, 0.f};
    c = mfma16(ldA(peu1, (mt * 6 + 0) * 64 + lane), bt0, c);
    c = mfma16(ldA(peu1, (mt * 6 + 1) * 64 + lane), bt1, c);
#pragma unroll
    for (int s = 0; s < 4; ++s)
      c = mfma16(ldA(peu1, (mt * 6 + 2 + s) * 64 + lane), bx[s], c);
    float4 bias = *reinterpret_cast<const float4*>(&beu1[mt * 16 + g * 4]);
    float4 cv = {c[0] + bias.x, c[1] + bias.y, c[2] + bias.z, c[3] + bias.w};
    cv.x = cv.x > 0.f ? cv.x : 0.f;  cv.y = cv.y > 0.f ? cv.y : 0.f;
    cv.z = cv.z > 0.f ? cv.z : 0.f;  cv.w = cv.w > 0.f ? cv.w : 0.f;
    const int slot = (mt >> 1) & 1;
    *reinterpret_cast<ushort4*>(&tb[wid][e][slot * 32 + (mt & 1) * 16 + g * 4]) = cvt4(cv);
    if ((mt & 1) == 0 && mt >= 2) {
      const int kt = (mt - 2) >> 1;
      bf16x8 b4 = ldL(&tb[wid][e][(kt & 1) * 32 + koff]);
#pragma unroll
      for (int mo = 0; mo < 4; ++mo)
        acc4[mo] = mfma16(ldA(peu2, (mo * 8 + kt) * 64 + lane), b4, acc4[mo]);
    }
    if ((mt & 3) == 3) __builtin_amdgcn_s_barrier();
  }
  {
    bf16x8 b4 = ldL(&tb[wid][e][32 + koff]);
#pragma unroll
    for (int mo = 0; mo < 4; ++mo)
      acc4[mo] = mfma16(ldA(peu2, (mo * 8 + 7) * 64 + lane), b4, acc4[mo]);
  }

  // ---- epilogue: he_new = he + a2@w_eu2 + b; store + atomic scatter ----
  {
    const float nv = nrm[eg];
    const int dn = edst[eg];
#pragma unroll
    for (int mo = 0; mo < 4; ++mo) {
      float4 hres = *reinterpret_cast<const float4*>(he + (size_t)eg * 64 + mo * 16 + g * 4);
      float4 bb = *reinterpret_cast<const float4*>(&beu2[mo * 16 + g * 4]);
      float4 vout = {acc4[mo][0] + bb.x + hres.x, acc4[mo][1] + bb.y + hres.y,
                     acc4[mo][2] + bb.z + hres.z, acc4[mo][3] + bb.w + hres.w};
      *reinterpret_cast<float4*>(out_he + (size_t)eg * 64 + mo * 16 + g * 4) = vout;
      float* nfp = nf + (size_t)dn * 64 + mo * 16 + g * 4;
      atomicAdd(nfp + 0, vout.x * nv);
      atomicAdd(nfp + 1, vout.y * nv);
      atomicAdd(nfp + 2, vout.z * nv);
      atomicAdd(nfp + 3, vout.w * nv);
    }
  }
}

// Node MLP: hn_new = hn + relu([hn|node_ftr]@w_nl1+b)@w_nl2+b  (unchanged from R2)
__global__ __launch_bounds__(256, 3) void node_kernel(
    const float* __restrict__ hn, const float* __restrict__ nf,
    const unsigned short* __restrict__ pnl1, const float* __restrict__ bnl1,
    const unsigned short* __restrict__ pnl2, const float* __restrict__ bnl2,
    float* __restrict__ out) {
  __shared__ unsigned short xn[64][136];
  __shared__ unsigned short act[64][264];
  const int tid = threadIdx.x, lane = tid & 63, wid = tid >> 6;
  const int nb = blockIdx.x * 64;
  const int arow = lane & 15, koff = (lane >> 4) << 3, r0 = (lane >> 4) << 2;
  {
    const int rrow = tid >> 2, q = tid & 3, cg = q << 4;
    const int gidx = nb + rrow;
    if (gidx < NNODES) {
      const float4* aP = reinterpret_cast<const float4*>(hn + (size_t)gidx * 64 + cg);
      const float4* bP = reinterpret_cast<const float4*>(nf + (size_t)gidx * 64 + cg);
#pragma unroll
      for (int i = 0; i < 4; ++i) {
        float4 a = aP[i], b = bP[i];
        *reinterpret_cast<ushort4*>(&xn[rrow][cg + i * 4])      = cvt4(a);
        *reinterpret_cast<ushort4*>(&xn[rrow][64 + cg + i * 4]) = cvt4(b);
      }
    } else {
      ushort4 z = make_ushort4(0, 0, 0, 0);
#pragma unroll
      for (int i = 0; i < 4; ++i) {
        *reinterpret_cast<ushort4*>(&xn[rrow][cg + i * 4]) = z;
        *reinterpret_cast<ushort4*>(&xn[rrow][64 + cg + i * 4]) = z;
      }
    }
  }
  __syncthreads();
  {
    f32x4 acc[4][4];
#pragma unroll
    for (int m = 0; m < 4; ++m)
#pragma unroll
      for (int n = 0; n < 4; ++n) acc[m][n] = (f32x4){0.f, 0.f, 0.f, 0.f};
#pragma unroll
    for (int ks = 0; ks < 4; ++ks) {
      bf16x8 a[4];
#pragma unroll
      for (int m = 0; m < 4; ++m)
        a[m] = ldL(&xn[m * 16 + arow][ks * 32 + koff]);
#pragma unroll
      for (int n = 0; n < 4; ++n) {
        bf16x8 b = ldA(pnl1, ((wid * 4 + n) * 4 + ks) * 64 + lane);
#pragma unroll
        for (int m = 0; m < 4; ++m) acc[m][n] = mfma16(a[m], b, acc[m][n]);
      }
    }
#pragma unroll
    for (int n = 0; n < 4; ++n) {
      const int col = wid * 64 + n * 16 + arow;
      const float bias = bnl1[col];
#pragma unroll
      for (int m = 0; m < 4; ++m)
#pragma unroll
        for (int r = 0; r < 4; ++r) {
          float v = acc[m][n][r] + bias;
          act[m * 16 + r0 + r][col] = bfr(v > 0.f ? v : 0.f);
        }
    }
  }
  __syncthreads();
  {
    f32x4 acc[4];
#pragma unroll
    for (int n = 0; n < 4; ++n) acc[n] = (f32x4){0.f, 0.f, 0.f, 0.f};
    const int mrow = wid * 16 + arow;
#pragma unroll
    for (int ks = 0; ks < 8; ++ks) {
      bf16x8 a = ldL(&act[mrow][ks * 32 + koff]);
#pragma unroll
      for (int n = 0; n < 4; ++n) {
        bf16x8 b = ldA(pnl2, (n * 8 + ks) * 64 + lane);
        acc[n] = mfma16(a, b, acc[n]);
      }
    }
#pragma unroll
    for (int r = 0; r < 4; ++r) {
      const int row = wid * 16 + r0 + r;
      const int gidx = nb + row;
      if (gidx < NNODES) {
#pragma unroll
        for (int n = 0; n < 4; ++n) {
          const int col = n * 16 + arow;
          out[(size_t)gidx * 64 + col] = bf2f(xn[row][col]) + acc[n][r] + bnl2[col];
        }
      }
    }
  }
}

extern "C" void kernel_launch(void* const* d_in, const int* in_sizes, int n_in,
                              void* d_out, int out_size, void* d_ws, size_t ws_size,
                              hipStream_t stream) {
  const float* hn   = (const float*)d_in[0];
  const float* he   = (const float*)d_in[1];
  const float* fe   = (const float*)d_in[2];
  const float* fes  = (const float*)d_in[3];
  const float* nrm  = (const float*)d_in[4];
  const int*   esrc = (const int*)d_in[5];
  const int*   edst = (const int*)d_in[6];
  const float* w_ev1 = (const float*)d_in[7];  const float* b_ev1 = (const float*)d_in[8];
  const float* w_ev2 = (const float*)d_in[9];  const float* b_ev2 = (const float*)d_in[10];
  const float* w_tp  = (const float*)d_in[11]; const float* b_tp  = (const float*)d_in[12];
  const float* w_eu1 = (const float*)d_in[13]; const float* b_eu1 = (const float*)d_in[14];
  const float* w_eu2 = (const float*)d_in[15]; const float* b_eu2 = (const float*)d_in[16];
  const float* w_nl1 = (const float*)d_in[17]; const float* b_nl1 = (const float*)d_in[18];
  const float* w_nl2 = (const float*)d_in[19]; const float* b_nl2 = (const float*)d_in[20];

  float* out = (float*)d_out;
  char* ws = (char*)d_ws;
  float* nfp = (float*)ws;
  size_t off = (size_t)NNODES * CDIM * sizeof(float);
  unsigned short* pev1 = (unsigned short*)(ws + off); off += (size_t)16 * 6 * 512 * 2;
  unsigned short* peu1 = (unsigned short*)(ws + off); off += (size_t)16 * 6 * 512 * 2;
  unsigned short* pev2 = (unsigned short*)(ws + off); off += (size_t)1 * 8 * 512 * 2;
  unsigned short* peu2 = (unsigned short*)(ws + off); off += (size_t)4 * 8 * 512 * 2;
  unsigned short* ptp  = (unsigned short*)(ws + off); off += (size_t)4 * 2 * 512 * 2;
  unsigned short* pnl1 = (unsigned short*)(ws + off); off += (size_t)16 * 4 * 512 * 2;
  unsigned short* pnl2 = (unsigned short*)(ws + off); off += (size_t)4 * 8 * 512 * 2;

  hipMemsetAsync(nfp, 0, (size_t)NNODES * CDIM * sizeof(float), stream);

  pack_all_kernel<<<84, 256, 0, stream>>>(
      w_ev1, w_eu1, w_nl1, w_eu2, w_nl2, w_ev2, w_tp,
      pev1, peu1, pnl1, peu2, pnl2, pev2, ptp);

  edge_kernel<<<NEDGES / 64, 256, 0, stream>>>(
      hn, he, fe, fes, nrm, esrc, edst,
      pev1, b_ev1, pev2, b_ev2, ptp, b_tp, peu1, b_eu1, peu2, b_eu2,
      out + (size_t)NNODES * CDIM, nfp);

  node_kernel<<<(NNODES + 63) / 64, 256, 0, stream>>>(
      hn, nfp, pnl1, b_nl1, pnl2, b_nl2, out);
}

// Round 4
// 787.470 us; speedup vs baseline: 1.2829x; 1.2829x over previous
//
#include <hip/hip_runtime.h>
#include <stdint.h>

#define NNODES 50000
#define NEDGES 800000
#define CDIM   64
#define SHD    9
#define EBD    16

using f32x4  = __attribute__((ext_vector_type(4))) float;
using bf16x8 = __attribute__((ext_vector_type(8))) __bf16;

static __device__ __forceinline__ unsigned short bfr(float x) {
  union { __bf16 b; unsigned short u; } t;
  t.b = (__bf16)x;            // native cvt (compiler emits v_cvt_pk_bf16_f32 pairs)
  return t.u;
}
static __device__ __forceinline__ float bf2f(unsigned short b) {
  union { unsigned u; float f; } v; v.u = ((unsigned)b) << 16;
  return v.f;
}
static __device__ __forceinline__ f32x4 mfma16(bf16x8 a, bf16x8 b, f32x4 c) {
  return __builtin_amdgcn_mfma_f32_16x16x32_bf16(a, b, c, 0, 0, 0);
}
static __device__ __forceinline__ ushort4 cvt4(float4 v) {
  return make_ushort4(bfr(v.x), bfr(v.y), bfr(v.z), bfr(v.w));
}
static __device__ __forceinline__ bf16x8 ldA(const unsigned short* __restrict__ p, int idx) {
  union { uint4 q; bf16x8 v; } t;
  t.q = reinterpret_cast<const uint4*>(p)[idx];
  return t.v;
}
static __device__ __forceinline__ bf16x8 ldL(const unsigned short* p) {
  union { uint4 q; bf16x8 v; } t;
  t.q = *reinterpret_cast<const uint4*>(p);
  return t.v;
}
static __device__ __forceinline__ float4 relu4(float4 v) {
  v.x = v.x > 0.f ? v.x : 0.f; v.y = v.y > 0.f ? v.y : 0.f;
  v.z = v.z > 0.f ? v.z : 0.f; v.w = v.w > 0.f ? v.w : 0.f;
  return v;
}

// Pack fp32 w[K][N] -> bf16 fragment order (same layout works as A- or B-operand):
// dst[((nt*KS+ks)*64+lane)*8+j] = w[rowmap(ks*32+(lane>>4)*8+j)][nt*16+(lane&15)]
// mode 1 (w_tp): vt col space [v16|fe9|z3|fes16|z20] -> w rows {c, c-7, c-10}.
__global__ void pack_all_kernel(
    const float* __restrict__ wev1, const float* __restrict__ weu1,
    const float* __restrict__ wnl1, const float* __restrict__ weu2,
    const float* __restrict__ wnl2, const float* __restrict__ wev2,
    const float* __restrict__ wtp,
    unsigned short* __restrict__ pev1, unsigned short* __restrict__ peu1,
    unsigned short* __restrict__ pnl1, unsigned short* __restrict__ peu2,
    unsigned short* __restrict__ pnl2, unsigned short* __restrict__ pev2,
    unsigned short* __restrict__ ptp) {
  int b = blockIdx.x;
  const float* w; unsigned short* dst; int K, N, KS, NT, base, mode = 0;
  if (b < 24)      { w = wev1; dst = pev1; K = 192; N = 256; KS = 6; NT = 16; base = 0; }
  else if (b < 48) { w = weu1; dst = peu1; K = 192; N = 256; KS = 6; NT = 16; base = 24; }
  else if (b < 64) { w = wnl1; dst = pnl1; K = 128; N = 256; KS = 4; NT = 16; base = 48; }
  else if (b < 72) { w = weu2; dst = peu2; K = 256; N = 64;  KS = 8; NT = 4;  base = 64; }
  else if (b < 80) { w = wnl2; dst = pnl2; K = 256; N = 64;  KS = 8; NT = 4;  base = 72; }
  else if (b < 82) { w = wev2; dst = pev2; K = 256; N = 9;   KS = 8; NT = 1;  base = 80; }
  else             { w = wtp;  dst = ptp;  K = 34;  N = 64;  KS = 2; NT = 4;  base = 82; mode = 1; }
  int idx = (b - base) * 256 + threadIdx.x;
  int total = NT * KS * 64;
  if (idx >= total) return;
  int lane = idx & 63;
  int t = idx >> 6;
  int ks = t % KS;
  int nt = t / KS;
  int n  = nt * 16 + (lane & 15);
  int kb = ks * 32 + ((lane >> 4) << 3);
  unsigned short v[8];
#pragma unroll
  for (int jj = 0; jj < 8; ++jj) {
    int k = kb + jj;
    int rm;
    if (mode == 0) rm = (k < K) ? k : -1;
    else rm = (k < 9) ? k : (k >= 16 && k <= 24) ? k - 7 : (k >= 28 && k <= 43) ? k - 10 : -1;
    float val = (rm >= 0 && n < N) ? w[(size_t)rm * N + n] : 0.f;
    v[jj] = bfr(val);
  }
  uint4 pk;
  pk.x = (unsigned)v[0] | ((unsigned)v[1] << 16);
  pk.y = (unsigned)v[2] | ((unsigned)v[3] << 16);
  pk.z = (unsigned)v[4] | ((unsigned)v[5] << 16);
  pk.w = (unsigned)v[6] | ((unsigned)v[7] << 16);
  reinterpret_cast<uint4*>(dst)[idx] = pk;
}

// Swapped-operand, block-cooperative edge pipeline.
// 64 edges/block, 4 waves. Wave wid = (we=wid>>1 edge-half, wm=wid&1 feat-half).
// Big GEMMs: weights as A (m-tiles split by wm), x^T as persistent B-frags for
// the wave's 2 edge-groups. Small GEMMs + epilogue: wave owns edge-group wid.
// C layout everywhere: col=lane&15 (edge), row=(lane>>4)*4+reg (feature)
// -> ushort4 LDS writes, b128 frag reads, float4 global stores.
__global__ __launch_bounds__(256, 3) void edge_kernel(
    const float* __restrict__ hn, const float* __restrict__ he,
    const float* __restrict__ fe, const float* __restrict__ fes,
    const float* __restrict__ nrm,
    const int* __restrict__ esrc, const int* __restrict__ edst,
    const unsigned short* __restrict__ pev1, const float* __restrict__ bev1,
    const unsigned short* __restrict__ pev2, const float* __restrict__ bev2,
    const unsigned short* __restrict__ ptp,  const float* __restrict__ btp,
    const unsigned short* __restrict__ peu1, const float* __restrict__ beu1,
    const unsigned short* __restrict__ peu2, const float* __restrict__ beu2,
    float* __restrict__ out_he, float* __restrict__ nf) {
  __shared__ unsigned short xa[64][200];   // [he|hs|hd] bf16 per edge
  __shared__ unsigned short vt[64][72];    // [v16|fe9|z3|fes16|z20]; later t (cols 0..63)
  __shared__ unsigned short act[64][136];  // hidden activations, one 128-feat half

  const int tid  = threadIdx.x;
  const int lane = tid & 63;
  const int wid  = tid >> 6;
  const int eb   = blockIdx.x * 64;
  const int e    = lane & 15;
  const int j    = lane >> 4;          // 0..3
  const int koff = j << 3;             // frag k-offset in shorts
  const int wm   = wid & 1;            // feature-half within a 128-col act half
  const int g0   = wid & 6;            // = 2*(wid>>1): first of this wave's 2 edge-groups
  const int ew   = (wid << 4) + e;     // own edge row (own group == wid)
  const int eg   = eb + ew;

  // ---- staging: thread t stages edge t>>2 (coalesced float4 + vector cvt) ----
  {
    const int et  = tid >> 2;
    const int q   = tid & 3;
    const int cg  = q << 4;
    const int ege = eb + et;
    const int src = esrc[ege];
    const int dst = edst[ege];
    const float4* heP = reinterpret_cast<const float4*>(he + (size_t)ege * 64 + cg);
    const float4* hsP = reinterpret_cast<const float4*>(hn + (size_t)src * 64 + cg);
    const float4* hdP = reinterpret_cast<const float4*>(hn + (size_t)dst * 64 + cg);
#pragma unroll
    for (int i = 0; i < 4; ++i) {
      float4 a = heP[i], b = hsP[i], d = hdP[i];
      *reinterpret_cast<ushort4*>(&xa[et][cg + i * 4])       = cvt4(a);
      *reinterpret_cast<ushort4*>(&xa[et][64 + cg + i * 4])  = cvt4(b);
      *reinterpret_cast<ushort4*>(&xa[et][128 + cg + i * 4]) = cvt4(d);
    }
    uint4 z = {0, 0, 0, 0};
    *reinterpret_cast<uint4*>(&vt[et][cg])     = z;
    *reinterpret_cast<uint4*>(&vt[et][cg + 8]) = z;
    vt[et][16 + q]     = bfr(fe[(size_t)ege * SHD + q]);
    vt[et][16 + q + 4] = bfr(fe[(size_t)ege * SHD + q + 4]);
    if (q == 0) vt[et][24] = bfr(fe[(size_t)ege * SHD + 8]);
    float4 fs = *reinterpret_cast<const float4*>(fes + (size_t)ege * EBD + q * 4);
    *reinterpret_cast<ushort4*>(&vt[et][28 + q * 4]) = cvt4(fs);
  }
  __syncthreads();   // S1: xa visible to all waves

  // ---- persistent x^T B-fragments for this wave's 2 edge-groups ----
  bf16x8 bhe[2][2];   // he feats 0..63   (dead after GEMM1)
  bf16x8 bhh[2][4];   // hs|hd feats 64..191 (live through GEMM3)
#pragma unroll
  for (int gl = 0; gl < 2; ++gl) {
    const unsigned short* xr = &xa[(g0 + gl) * 16 + e][0];
    bhe[gl][0] = ldL(xr + koff);
    bhe[gl][1] = ldL(xr + 32 + koff);
#pragma unroll
    for (int s = 0; s < 4; ++s) bhh[gl][s] = ldL(xr + 64 + s * 32 + koff);
  }

  // ---- GEMM1 (a1^T, m-tiles split by wm) fused with GEMM2 (v, own edges) ----
  f32x4 accv = (f32x4){0.f, 0.f, 0.f, 0.f};
#pragma unroll
  for (int h = 0; h < 2; ++h) {
    for (int ml = 0; ml < 4; ++ml) {
      const int mt = h * 8 + wm * 4 + ml;
      f32x4 c0 = (f32x4){0.f, 0.f, 0.f, 0.f};
      f32x4 c1 = (f32x4){0.f, 0.f, 0.f, 0.f};
#pragma unroll
      for (int s = 0; s < 6; ++s) {
        bf16x8 a = ldA(pev1, (mt * 6 + s) * 64 + lane);
        c0 = mfma16(a, (s < 2) ? bhe[0][s] : bhh[0][s - 2], c0);
        c1 = mfma16(a, (s < 2) ? bhe[1][s] : bhh[1][s - 2], c1);
      }
      float4 bias = *reinterpret_cast<const float4*>(bev1 + mt * 16 + j * 4);
      float4 v0 = relu4(make_float4(c0[0] + bias.x, c0[1] + bias.y, c0[2] + bias.z, c0[3] + bias.w));
      float4 v1 = relu4(make_float4(c1[0] + bias.x, c1[1] + bias.y, c1[2] + bias.z, c1[3] + bias.w));
      const int col = (wm * 4 + ml) * 16 + j * 4;
      *reinterpret_cast<ushort4*>(&act[g0 * 16 + e][col])       = cvt4(v0);
      *reinterpret_cast<ushort4*>(&act[(g0 + 1) * 16 + e][col]) = cvt4(v1);
    }
    __syncthreads();   // act half complete
#pragma unroll
    for (int sl = 0; sl < 4; ++sl) {
      bf16x8 b = ldL(&act[ew][sl * 32 + koff]);
      accv = mfma16(ldA(pev2, (h * 4 + sl) * 64 + lane), b, accv);
    }
    __syncthreads();   // GEMM2 readers done before act reuse
  }

  // ---- v -> vt cols 0..15 (cols >= 9 zeroed), own rows; then GEMM_t ----
  {
    float4 bv = {0.f, 0.f, 0.f, 0.f};
    if (j < 2)       bv = *reinterpret_cast<const float4*>(bev2 + j * 4);
    else if (j == 2) bv.x = bev2[8];
    float vals[4] = {accv[0] + bv.x, accv[1] + bv.y, accv[2] + bv.z, accv[3] + bv.w};
    ushort4 uv;
    uv.x = (j * 4 + 0 < 9) ? bfr(vals[0]) : (unsigned short)0;
    uv.y = (j * 4 + 1 < 9) ? bfr(vals[1]) : (unsigned short)0;
    uv.z = (j * 4 + 2 < 9) ? bfr(vals[2]) : (unsigned short)0;
    uv.w = (j * 4 + 3 < 9) ? bfr(vals[3]) : (unsigned short)0;
    *reinterpret_cast<ushort4*>(&vt[ew][j * 4]) = uv;
  }
  {
    bf16x8 btv0 = ldL(&vt[ew][koff]);        // in-order within wave
    bf16x8 btv1 = ldL(&vt[ew][32 + koff]);
#pragma unroll
    for (int mt = 0; mt < 4; ++mt) {
      f32x4 c = (f32x4){0.f, 0.f, 0.f, 0.f};
      c = mfma16(ldA(ptp, (mt * 2 + 0) * 64 + lane), btv0, c);
      c = mfma16(ldA(ptp, (mt * 2 + 1) * 64 + lane), btv1, c);
      float4 bias = *reinterpret_cast<const float4*>(btp + mt * 16 + j * 4);
      float4 cv = {c[0] + bias.x, c[1] + bias.y, c[2] + bias.z, c[3] + bias.w};
      *reinterpret_cast<ushort4*>(&vt[ew][mt * 16 + j * 4]) = cvt4(cv);  // t overwrites v|fe|fes
    }
  }
  __syncthreads();   // S5: t visible to all waves

  bf16x8 bt[2][2];   // t^T frags for this wave's 2 edge-groups
#pragma unroll
  for (int gl = 0; gl < 2; ++gl) {
    const unsigned short* tr = &vt[(g0 + gl) * 16 + e][0];
    bt[gl][0] = ldL(tr + koff);
    bt[gl][1] = ldL(tr + 32 + koff);
  }

  // ---- GEMM3 (a2^T) fused with GEMM4 (he_delta, own edges) ----
  f32x4 acc4[4];
#pragma unroll
  for (int mo = 0; mo < 4; ++mo) acc4[mo] = (f32x4){0.f, 0.f, 0.f, 0.f};
#pragma unroll
  for (int h = 0; h < 2; ++h) {
    for (int ml = 0; ml < 4; ++ml) {
      const int mt = h * 8 + wm * 4 + ml;
      f32x4 c0 = (f32x4){0.f, 0.f, 0.f, 0.f};
      f32x4 c1 = (f32x4){0.f, 0.f, 0.f, 0.f};
#pragma unroll
      for (int s = 0; s < 6; ++s) {
        bf16x8 a = ldA(peu1, (mt * 6 + s) * 64 + lane);
        c0 = mfma16(a, (s < 2) ? bt[0][s] : bhh[0][s - 2], c0);
        c1 = mfma16(a, (s < 2) ? bt[1][s] : bhh[1][s - 2], c1);
      }
      float4 bias = *reinterpret_cast<const float4*>(beu1 + mt * 16 + j * 4);
      float4 v0 = relu4(make_float4(c0[0] + bias.x, c0[1] + bias.y, c0[2] + bias.z, c0[3] + bias.w));
      float4 v1 = relu4(make_float4(c1[0] + bias.x, c1[1] + bias.y, c1[2] + bias.z, c1[3] + bias.w));
      const int col = (wm * 4 + ml) * 16 + j * 4;
      *reinterpret_cast<ushort4*>(&act[g0 * 16 + e][col])       = cvt4(v0);
      *reinterpret_cast<ushort4*>(&act[(g0 + 1) * 16 + e][col]) = cvt4(v1);
    }
    __syncthreads();
#pragma unroll
    for (int sl = 0; sl < 4; ++sl) {
      bf16x8 b = ldL(&act[ew][sl * 32 + koff]);
#pragma unroll
      for (int mo = 0; mo < 4; ++mo)
        acc4[mo] = mfma16(ldA(peu2, (mo * 8 + h * 4 + sl) * 64 + lane), b, acc4[mo]);
    }
    if (h == 0) __syncthreads();
  }

  // ---- epilogue: he_new = he + delta; float4 store + atomic scatter ----
  {
    const float nv = nrm[eg];
    const int dn = edst[eg];
#pragma unroll
    for (int mo = 0; mo < 4; ++mo) {
      ushort4 hres = *reinterpret_cast<const ushort4*>(&xa[ew][mo * 16 + j * 4]);
      float4 bb = *reinterpret_cast<const float4*>(beu2 + mo * 16 + j * 4);
      float4 vout = {acc4[mo][0] + bb.x + bf2f(hres.x),
                     acc4[mo][1] + bb.y + bf2f(hres.y),
                     acc4[mo][2] + bb.z + bf2f(hres.z),
                     acc4[mo][3] + bb.w + bf2f(hres.w)};
      *reinterpret_cast<float4*>(out_he + (size_t)eg * 64 + mo * 16 + j * 4) = vout;
      float* nfp = nf + (size_t)dn * 64 + mo * 16 + j * 4;
      atomicAdd(nfp + 0, vout.x * nv);
      atomicAdd(nfp + 1, vout.y * nv);
      atomicAdd(nfp + 2, vout.z * nv);
      atomicAdd(nfp + 3, vout.w * nv);
    }
  }
}

// Node MLP: hn_new = hn + relu([hn|node_ftr]@w_nl1+b)@w_nl2+b
__global__ __launch_bounds__(256, 3) void node_kernel(
    const float* __restrict__ hn, const float* __restrict__ nf,
    const unsigned short* __restrict__ pnl1, const float* __restrict__ bnl1,
    const unsigned short* __restrict__ pnl2, const float* __restrict__ bnl2,
    float* __restrict__ out) {
  __shared__ unsigned short xn[64][136];
  __shared__ unsigned short act[64][264];
  const int tid = threadIdx.x, lane = tid & 63, wid = tid >> 6;
  const int nb = blockIdx.x * 64;
  const int arow = lane & 15, koff = (lane >> 4) << 3, r0 = (lane >> 4) << 2;
  {
    const int rrow = tid >> 2, q = tid & 3, cg = q << 4;
    const int gidx = nb + rrow;
    if (gidx < NNODES) {
      const float4* aP = reinterpret_cast<const float4*>(hn + (size_t)gidx * 64 + cg);
      const float4* bP = reinterpret_cast<const float4*>(nf + (size_t)gidx * 64 + cg);
#pragma unroll
      for (int i = 0; i < 4; ++i) {
        float4 a = aP[i], b = bP[i];
        *reinterpret_cast<ushort4*>(&xn[rrow][cg + i * 4])      = cvt4(a);
        *reinterpret_cast<ushort4*>(&xn[rrow][64 + cg + i * 4]) = cvt4(b);
      }
    } else {
      ushort4 z = make_ushort4(0, 0, 0, 0);
#pragma unroll
      for (int i = 0; i < 4; ++i) {
        *reinterpret_cast<ushort4*>(&xn[rrow][cg + i * 4]) = z;
        *reinterpret_cast<ushort4*>(&xn[rrow][64 + cg + i * 4]) = z;
      }
    }
  }
  __syncthreads();
  {
    f32x4 acc[4][4];
#pragma unroll
    for (int m = 0; m < 4; ++m)
#pragma unroll
      for (int n = 0; n < 4; ++n) acc[m][n] = (f32x4){0.f, 0.f, 0.f, 0.f};
#pragma unroll
    for (int ks = 0; ks < 4; ++ks) {
      bf16x8 a[4];
#pragma unroll
      for (int m = 0; m < 4; ++m)
        a[m] = ldL(&xn[m * 16 + arow][ks * 32 + koff]);
#pragma unroll
      for (int n = 0; n < 4; ++n) {
        bf16x8 b = ldA(pnl1, ((wid * 4 + n) * 4 + ks) * 64 + lane);
#pragma unroll
        for (int m = 0; m < 4; ++m) acc[m][n] = mfma16(a[m], b, acc[m][n]);
      }
    }
#pragma unroll
    for (int n = 0; n < 4; ++n) {
      const int col = wid * 64 + n * 16 + arow;
      const float bias = bnl1[col];
#pragma unroll
      for (int m = 0; m < 4; ++m)
#pragma unroll
        for (int r = 0; r < 4; ++r) {
          float v = acc[m][n][r] + bias;
          act[m * 16 + r0 + r][col] = bfr(v > 0.f ? v : 0.f);
        }
    }
  }
  __syncthreads();
  {
    f32x4 acc[4];
#pragma unroll
    for (int n = 0; n < 4; ++n) acc[n] = (f32x4){0.f, 0.f, 0.f, 0.f};
    const int mrow = wid * 16 + arow;
#pragma unroll
    for (int ks = 0; ks < 8; ++ks) {
      bf16x8 a = ldL(&act[mrow][ks * 32 + koff]);
#pragma unroll
      for (int n = 0; n < 4; ++n) {
        bf16x8 b = ldA(pnl2, (n * 8 + ks) * 64 + lane);
        acc[n] = mfma16(a, b, acc[n]);
      }
    }
#pragma unroll
    for (int r = 0; r < 4; ++r) {
      const int row = wid * 16 + r0 + r;
      const int gidx = nb + row;
      if (gidx < NNODES) {
#pragma unroll
        for (int n = 0; n < 4; ++n) {
          const int col = n * 16 + arow;
          out[(size_t)gidx * 64 + col] = bf2f(xn[row][col]) + acc[n][r] + bnl2[col];
        }
      }
    }
  }
}

extern "C" void kernel_launch(void* const* d_in, const int* in_sizes, int n_in,
                              void* d_out, int out_size, void* d_ws, size_t ws_size,
                              hipStream_t stream) {
  const float* hn   = (const float*)d_in[0];
  const float* he   = (const float*)d_in[1];
  const float* fe   = (const float*)d_in[2];
  const float* fes  = (const float*)d_in[3];
  const float* nrm  = (const float*)d_in[4];
  const int*   esrc = (const int*)d_in[5];
  const int*   edst = (const int*)d_in[6];
  const float* w_ev1 = (const float*)d_in[7];  const float* b_ev1 = (const float*)d_in[8];
  const float* w_ev2 = (const float*)d_in[9];  const float* b_ev2 = (const float*)d_in[10];
  const float* w_tp  = (const float*)d_in[11]; const float* b_tp  = (const float*)d_in[12];
  const float* w_eu1 = (const float*)d_in[13]; const float* b_eu1 = (const float*)d_in[14];
  const float* w_eu2 = (const float*)d_in[15]; const float* b_eu2 = (const float*)d_in[16];
  const float* w_nl1 = (const float*)d_in[17]; const float* b_nl1 = (const float*)d_in[18];
  const float* w_nl2 = (const float*)d_in[19]; const float* b_nl2 = (const float*)d_in[20];

  float* out = (float*)d_out;
  char* ws = (char*)d_ws;
  float* nfp = (float*)ws;
  size_t off = (size_t)NNODES * CDIM * sizeof(float);
  unsigned short* pev1 = (unsigned short*)(ws + off); off += (size_t)16 * 6 * 512 * 2;
  unsigned short* peu1 = (unsigned short*)(ws + off); off += (size_t)16 * 6 * 512 * 2;
  unsigned short* pev2 = (unsigned short*)(ws + off); off += (size_t)1 * 8 * 512 * 2;
  unsigned short* peu2 = (unsigned short*)(ws + off); off += (size_t)4 * 8 * 512 * 2;
  unsigned short* ptp  = (unsigned short*)(ws + off); off += (size_t)4 * 2 * 512 * 2;
  unsigned short* pnl1 = (unsigned short*)(ws + off); off += (size_t)16 * 4 * 512 * 2;
  unsigned short* pnl2 = (unsigned short*)(ws + off); off += (size_t)4 * 8 * 512 * 2;

  hipMemsetAsync(nfp, 0, (size_t)NNODES * CDIM * sizeof(float), stream);

  pack_all_kernel<<<84, 256, 0, stream>>>(
      w_ev1, w_eu1, w_nl1, w_eu2, w_nl2, w_ev2, w_tp,
      pev1, peu1, pnl1, peu2, pnl2, pev2, ptp);

  edge_kernel<<<NEDGES / 64, 256, 0, stream>>>(
      hn, he, fe, fes, nrm, esrc, edst,
      pev1, b_ev1, pev2, b_ev2, ptp, b_tp, peu1, b_eu1, peu2, b_eu2,
      out + (size_t)NNODES * CDIM, nfp);

  node_kernel<<<(NNODES + 63) / 64, 256, 0, stream>>>(
      hn, nfp, pnl1, b_nl1, pnl2, b_nl2, out);
}